// Round 17
// baseline (146.554 us; speedup 1.0000x reference)
//
#include <hip/hip_runtime.h>

#define N_NODES 80000
#define N_EDGES 1280000
#define F_IN 64
#define F_HID 128
#define F_OUT 40
#define NB 313             // src buckets (src>>8), 256 nodes each
#define B1 320             // edge-chunk blocks
#define CHUNK 4000         // edges per chunk block (320*4000 = 1.28M)
#define SAP 72             // sA bf16 stride (row 64 + pad 8)
#define SPP 136            // sP bf16 stride (row 128 + pad 8)

typedef __attribute__((ext_vector_type(8))) short bf16x8;
typedef __attribute__((ext_vector_type(4))) float f32x4;
typedef __attribute__((ext_vector_type(4))) unsigned int u32x4;

__device__ __forceinline__ unsigned short bf16rn(float f) {
  unsigned u = __float_as_uint(f);
  u += 0x7fffu + ((u >> 16) & 1u);   // round-to-nearest-even
  return (unsigned short)(u >> 16);
}
__device__ __forceinline__ float bflo(unsigned w) { return __uint_as_float(w << 16); }
__device__ __forceinline__ float bfhi(unsigned w) { return __uint_as_float(w & 0xffff0000u); }

// ---- prep: x -> bf16 (blocks 0..4999) + W1/W2 MFMA-fragment pack (5000..5055) ----
__global__ __launch_bounds__(256) void prep_kernel(const float4* __restrict__ x4,
                                                   ushort4* __restrict__ xb4,
                                                   const float* __restrict__ W1,
                                                   const float* __restrict__ W2,
                                                   unsigned short* __restrict__ w1p,
                                                   unsigned short* __restrict__ w2p) {
  int b = blockIdx.x;
  if (b < 5000) {
    int i = b * 256 + threadIdx.x;     // < 1.28M exactly
    float4 v = x4[i];
    ushort4 o;
    o.x = bf16rn(v.x); o.y = bf16rn(v.y); o.z = bf16rn(v.z); o.w = bf16rn(v.w);
    xb4[i] = o;
  } else {
    int gidx = (b - 5000) * 256 + threadIdx.x;
    if (gidx < 8192) {
      int i = gidx & 7, l = (gidx >> 3) & 63, kf = (gidx >> 9) & 1, nt = gidx >> 10;
      int k = (l >> 4) * 8 + i + kf * 32;
      int c = nt * 16 + (l & 15);
      w1p[gidx] = bf16rn(W1[k * F_HID + c]);
    } else if (gidx < 8192 + 6144) {
      int idx = gidx - 8192;
      int i = idx & 7, l = (idx >> 3) & 63, kf = (idx >> 9) & 3, nt = idx >> 11;
      int k = (l >> 4) * 8 + i + kf * 32;
      int c = nt * 16 + (l & 15);
      w2p[idx] = (c < F_OUT) ? bf16rn(W2[k * F_OUT + c]) : (unsigned short)0;
    }
  }
}

// ---- histB: per-(block,bucket) counts only (LDS histogram, NO global atomics) ----
__global__ __launch_bounds__(256) void histB_kernel(const int* __restrict__ src,
                                                    int* __restrict__ counts) {
  __shared__ int h[NB];
  int tid = threadIdx.x;
  for (int i = tid; i < NB; i += 256) h[i] = 0;
  __syncthreads();
  int base = blockIdx.x * CHUNK;
  for (int i = base + tid; i < base + CHUNK; i += 256)
    atomicAdd(&h[src[i] >> 8], 1);
  __syncthreads();
  for (int i = tid; i < NB; i += 256) counts[blockIdx.x * NB + i] = h[i];
}

// --- scan2: per bucket b, exclusive-scan the 320 block counts; emit bucket total ---
__global__ __launch_bounds__(320) void scan2_kernel(int* __restrict__ counts,
                                                    int* __restrict__ btot) {
  __shared__ int wsum[5];
  __shared__ int woff[5];
  int b = blockIdx.x;
  int t = threadIdx.x, lane = t & 63, w = t >> 6;
  int v = counts[t * NB + b];
  int s = v;
#pragma unroll
  for (int off = 1; off < 64; off <<= 1) {
    int u = __shfl_up(s, off, 64);
    if (lane >= off) s += u;
  }
  if (lane == 63) wsum[w] = s;
  __syncthreads();
  if (t == 0) {
    int acc = 0;
#pragma unroll
    for (int i = 0; i < 5; ++i) { woff[i] = acc; acc += wsum[i]; }
    btot[b] = acc;
  }
  __syncthreads();
  counts[t * NB + b] = (s - v) + woff[w];
}

// --- scanT: one tiny block scans the 313 bucket totals -> bbase ---
__global__ __launch_bounds__(320) void scanT_kernel(const int* __restrict__ btot,
                                                    int* __restrict__ bbase,
                                                    int* __restrict__ rs) {
  __shared__ int wsum[5];
  __shared__ int woff[5];
  int t = threadIdx.x, lane = t & 63, w = t >> 6;
  int v = (t < NB) ? btot[t] : 0;
  int s = v;
#pragma unroll
  for (int off = 1; off < 64; off <<= 1) {
    int u = __shfl_up(s, off, 64);
    if (lane >= off) s += u;
  }
  if (lane == 63) wsum[w] = s;
  __syncthreads();
  if (t == 0) {
    int acc = 0;
#pragma unroll
    for (int i = 0; i < 5; ++i) { woff[i] = acc; acc += wsum[i]; }
  }
  __syncthreads();
  if (t < NB) bbase[t] = (s - v) + woff[w];
  if (t == 0) { bbase[NB] = N_EDGES; rs[N_NODES] = N_EDGES; }
}

// --- place: stream edges into bucket-grouped staging. Local node in dst bits 17..24.
__global__ __launch_bounds__(256) void place_kernel(
    const int* __restrict__ src, const int* __restrict__ dst,
    const float* __restrict__ vals, const int* __restrict__ off,
    const int* __restrict__ bbase, int2* __restrict__ estg) {
  __shared__ int cur[NB];
  int tid = threadIdx.x;
  for (int i = tid; i < NB; i += 256)
    cur[i] = off[blockIdx.x * NB + i] + bbase[i];
  __syncthreads();
  int base = blockIdx.x * CHUNK;
  for (int i = base + tid; i < base + CHUNK; i += 256) {
    int s = src[i];
    int d = __builtin_nontemporal_load(dst + i);
    float vv = __builtin_nontemporal_load(vals + i);
    int p = atomicAdd(&cur[s >> 8], 1);
    estg[p] = make_int2(d | ((s & 255) << 17), __float_as_int(vv));
  }
}

// --- permute: one block per bucket. Pass 1: per-node degree + block scan -> rs.
// Pass 2: scatter staged edges to final slots (one XCD per 32KB window).
__global__ __launch_bounds__(512) void permute_kernel(const int* __restrict__ bbase,
                                                      const int2* __restrict__ estg,
                                                      int2* __restrict__ epack,
                                                      int* __restrict__ rs) {
  __shared__ int cnt[256];
  __shared__ int cur[256];
  __shared__ int wsum[4];
  __shared__ int woff[4];
  int b = blockIdx.x, tid = threadIdx.x;
  int nb0 = b << 8;
  int ebase = bbase[b], eend = bbase[b + 1];
  if (tid < 256) cnt[tid] = 0;
  __syncthreads();
  for (int e = ebase + tid; e < eend; e += 512) {
    int2 v = estg[e];
    atomicAdd(&cnt[(v.x >> 17) & 255], 1);
  }
  __syncthreads();
  int lane = tid & 63, w = tid >> 6;
  int v = (tid < 256) ? cnt[tid] : 0;
  int s = v;
#pragma unroll
  for (int off = 1; off < 64; off <<= 1) {
    int u = __shfl_up(s, off, 64);
    if (lane >= off) s += u;
  }
  if (tid < 256 && lane == 63) wsum[w] = s;
  __syncthreads();
  if (tid == 0) {
    int acc = 0;
#pragma unroll
    for (int i = 0; i < 4; ++i) { woff[i] = acc; acc += wsum[i]; }
  }
  __syncthreads();
  if (tid < 256) {
    int g = ebase + woff[w] + (s - v);
    if (nb0 + tid < N_NODES) rs[nb0 + tid] = g;
    cur[tid] = g;
  }
  __syncthreads();
  for (int e = ebase + tid; e < eend; e += 512) {
    int2 v2 = estg[e];
    int p = atomicAdd(&cur[(v2.x >> 17) & 255], 1);
    epack[p] = make_int2(v2.x & 0x1FFFF, v2.y);
  }
}

// ------ gather1: one wave per row, barrier-free: sxgb[node] = bf16(A@xb row) ------
__global__ __launch_bounds__(256) void gather1_kernel(
    const int* __restrict__ rs, const int2* __restrict__ epack,
    const uint4* __restrict__ xb, uint4* __restrict__ sxgb) {
  int node = (blockIdx.x * 256 + threadIdx.x) >> 6;
  int lane = threadIdx.x & 63;
  if (node >= N_NODES) return;
  int h = lane >> 3;     // 0..7: which of 8 parallel edges
  int fi = lane & 7;     // feature-oct index (feats 8fi..8fi+7)
  int j0 = rs[node], j1 = rs[node + 1];
  float a0 = 0.f, a1 = 0.f, a2 = 0.f, a3 = 0.f;
  float a4 = 0.f, a5 = 0.f, a6 = 0.f, a7 = 0.f;
  const unsigned long long* ep = (const unsigned long long*)epack;
  int j = j0;
  for (; j + 16 <= j1; j += 16) {   // 16 edges in flight
    unsigned long long e0 = __builtin_nontemporal_load(ep + j + h);
    unsigned long long e1 = __builtin_nontemporal_load(ep + j + 8 + h);
    uint4 q0 = xb[(size_t)(unsigned)(e0 & 0x1FFFFu) * 8 + fi];
    uint4 q1 = xb[(size_t)(unsigned)(e1 & 0x1FFFFu) * 8 + fi];
    float v0 = __uint_as_float((unsigned)(e0 >> 32));
    float v1 = __uint_as_float((unsigned)(e1 >> 32));
    a0 += v0 * bflo(q0.x); a1 += v0 * bfhi(q0.x);
    a2 += v0 * bflo(q0.y); a3 += v0 * bfhi(q0.y);
    a4 += v0 * bflo(q0.z); a5 += v0 * bfhi(q0.z);
    a6 += v0 * bflo(q0.w); a7 += v0 * bfhi(q0.w);
    a0 += v1 * bflo(q1.x); a1 += v1 * bfhi(q1.x);
    a2 += v1 * bflo(q1.y); a3 += v1 * bfhi(q1.y);
    a4 += v1 * bflo(q1.z); a5 += v1 * bfhi(q1.z);
    a6 += v1 * bflo(q1.w); a7 += v1 * bfhi(q1.w);
  }
  for (; j + 8 <= j1; j += 8) {
    unsigned long long e = __builtin_nontemporal_load(ep + j + h);
    uint4 q = xb[(size_t)(unsigned)(e & 0x1FFFFu) * 8 + fi];
    float v = __uint_as_float((unsigned)(e >> 32));
    a0 += v * bflo(q.x); a1 += v * bfhi(q.x);
    a2 += v * bflo(q.y); a3 += v * bfhi(q.y);
    a4 += v * bflo(q.z); a5 += v * bfhi(q.z);
    a6 += v * bflo(q.w); a7 += v * bfhi(q.w);
  }
  if (h < j1 - j) {                 // tail 0..7 edges
    unsigned long long e = __builtin_nontemporal_load(ep + j + h);
    uint4 q = xb[(size_t)(unsigned)(e & 0x1FFFFu) * 8 + fi];
    float v = __uint_as_float((unsigned)(e >> 32));
    a0 += v * bflo(q.x); a1 += v * bfhi(q.x);
    a2 += v * bflo(q.y); a3 += v * bfhi(q.y);
    a4 += v * bflo(q.z); a5 += v * bfhi(q.z);
    a6 += v * bflo(q.w); a7 += v * bfhi(q.w);
  }
#pragma unroll
  for (int m = 8; m <= 32; m <<= 1) {
    a0 += __shfl_xor(a0, m, 64); a1 += __shfl_xor(a1, m, 64);
    a2 += __shfl_xor(a2, m, 64); a3 += __shfl_xor(a3, m, 64);
    a4 += __shfl_xor(a4, m, 64); a5 += __shfl_xor(a5, m, 64);
    a6 += __shfl_xor(a6, m, 64); a7 += __shfl_xor(a7, m, 64);
  }
  if (lane < 8) {
    u32x4 o;
    o.x = (unsigned)bf16rn(a0) | ((unsigned)bf16rn(a1) << 16);
    o.y = (unsigned)bf16rn(a2) | ((unsigned)bf16rn(a3) << 16);
    o.z = (unsigned)bf16rn(a4) | ((unsigned)bf16rn(a5) << 16);
    o.w = (unsigned)bf16rn(a6) | ((unsigned)bf16rn(a7) << 16);
    __builtin_nontemporal_store(o, (u32x4*)(sxgb + (size_t)node * 8 + fi));
  }
}

// ---- dense (MFMA): gb = bf16(relu(sX@W1)@W2), sX = 32 bf16 rows in LDS ----
__global__ __launch_bounds__(256) void dense_kernel(
    const uint4* __restrict__ sxgb, const uint4* __restrict__ w1p4,
    const uint4* __restrict__ w2p4, unsigned short* __restrict__ gb) {
  __shared__ __align__(16) unsigned short sA[32 * SAP];   // 4.6 KB
  __shared__ __align__(16) unsigned short sP[32 * SPP];   // 8.7 KB
  int tid = threadIdx.x, lane = tid & 63, w = tid >> 6;
  int rbase = blockIdx.x * 32;

  {                                   // stage 32 rows x 8 uint4, bf16 direct
    int row = tid >> 3, qi = tid & 7;
    uint4 q = sxgb[blockIdx.x * 256 + tid];
    *(uint4*)&sA[row * SAP + qi * 8] = q;
  }
  __syncthreads();

  int kg = lane >> 4;                 // k-group 0..3 (8 k each)
  int cl = lane & 15;                 // col-in-tile / row-in-tile

  // ---- phase 1: P = relu(A @ W1) ----
  {
    int mt = w & 1;                   // row tile
    int ntb = (w >> 1) * 4;           // col tiles ntb..ntb+3
    int arow = mt * 16 + cl;
    bf16x8 a0 = *(const bf16x8*)&sA[arow * SAP + kg * 8];
    bf16x8 a1 = *(const bf16x8*)&sA[arow * SAP + 32 + kg * 8];
    int prow = mt * 16 + kg * 4;
#pragma unroll
    for (int t = 0; t < 4; ++t) {
      int nt = ntb + t;
      f32x4 acc = {0.f, 0.f, 0.f, 0.f};
      bf16x8 b0 = *(const bf16x8*)&w1p4[(nt * 2 + 0) * 64 + lane];
      bf16x8 b1 = *(const bf16x8*)&w1p4[(nt * 2 + 1) * 64 + lane];
      acc = __builtin_amdgcn_mfma_f32_16x16x32_bf16(a0, b0, acc, 0, 0, 0);
      acc = __builtin_amdgcn_mfma_f32_16x16x32_bf16(a1, b1, acc, 0, 0, 0);
      int pcol = nt * 16 + cl;
#pragma unroll
      for (int r = 0; r < 4; ++r)
        sP[(prow + r) * SPP + pcol] = bf16rn(fmaxf(acc[r], 0.f));
    }
  }
  __syncthreads();

  // ---- phase 2: out = P @ W2 (N padded to 48, write cols < 40) ----
  {
    int nT = (w < 2) ? 2 : 1;         // waves 0,1: 2 tiles; waves 2,3: 1 tile
    for (int s = 0; s < nT; ++s) {
      int T = w + s * 4;              // 0..5
      int mt = T & 1, nt = T >> 1;
      int arow = mt * 16 + cl;
      f32x4 acc = {0.f, 0.f, 0.f, 0.f};
#pragma unroll
      for (int kf = 0; kf < 4; ++kf) {
        bf16x8 a = *(const bf16x8*)&sP[arow * SPP + kf * 32 + kg * 8];
        bf16x8 b = *(const bf16x8*)&w2p4[(nt * 4 + kf) * 64 + lane];
        acc = __builtin_amdgcn_mfma_f32_16x16x32_bf16(a, b, acc, 0, 0, 0);
      }
      int ocol = nt * 16 + cl;
      if (ocol < F_OUT) {
        int orow = rbase + mt * 16 + kg * 4;
#pragma unroll
        for (int r = 0; r < 4; ++r)
          gb[(size_t)(orow + r) * F_OUT + ocol] = bf16rn(acc[r]);
      }
    }
  }
}

// ------- SPMM2 gather: out = A @ gb (40 bf16 feats = 5 lanes x uint4) -------
__global__ __launch_bounds__(256) void spmm2_kernel(
    const int* __restrict__ rs, const int2* __restrict__ epack,
    const uint4* __restrict__ gb4, float* __restrict__ out) {
  int node = (blockIdx.x * 256 + threadIdx.x) >> 6;
  int lane = threadIdx.x & 63;
  if (node >= N_NODES) return;
  int grp = lane / 5;         // 0..11 live, 12 = idle (lanes 60-63)
  int fi = lane % 5;          // feature oct (feats 8fi..8fi+7)
  bool active = grp < 12;
  int j0 = rs[node], j1 = rs[node + 1];
  float a0 = 0.f, a1 = 0.f, a2 = 0.f, a3 = 0.f;
  float a4 = 0.f, a5 = 0.f, a6 = 0.f, a7 = 0.f;
  const unsigned long long* ep = (const unsigned long long*)epack;
  int j = j0;
  for (; j + 24 <= j1; j += 24) {   // 24 edges in flight
    if (active) {
      unsigned long long e0 = __builtin_nontemporal_load(ep + j + grp);
      unsigned long long e1 = __builtin_nontemporal_load(ep + j + 12 + grp);
      uint4 q0 = gb4[(size_t)(unsigned)(e0 & 0x1FFFFu) * 5 + fi];
      uint4 q1 = gb4[(size_t)(unsigned)(e1 & 0x1FFFFu) * 5 + fi];
      float v0 = __uint_as_float((unsigned)(e0 >> 32));
      float v1 = __uint_as_float((unsigned)(e1 >> 32));
      a0 += v0 * bflo(q0.x); a1 += v0 * bfhi(q0.x);
      a2 += v0 * bflo(q0.y); a3 += v0 * bfhi(q0.y);
      a4 += v0 * bflo(q0.z); a5 += v0 * bfhi(q0.z);
      a6 += v0 * bflo(q0.w); a7 += v0 * bfhi(q0.w);
      a0 += v1 * bflo(q1.x); a1 += v1 * bfhi(q1.x);
      a2 += v1 * bflo(q1.y); a3 += v1 * bfhi(q1.y);
      a4 += v1 * bflo(q1.z); a5 += v1 * bfhi(q1.z);
      a6 += v1 * bflo(q1.w); a7 += v1 * bfhi(q1.w);
    }
  }
  for (; j + 12 <= j1; j += 12) {
    if (active) {
      unsigned long long e = __builtin_nontemporal_load(ep + j + grp);
      uint4 q = gb4[(size_t)(unsigned)(e & 0x1FFFFu) * 5 + fi];
      float v = __uint_as_float((unsigned)(e >> 32));
      a0 += v * bflo(q.x); a1 += v * bfhi(q.x);
      a2 += v * bflo(q.y); a3 += v * bfhi(q.y);
      a4 += v * bflo(q.z); a5 += v * bfhi(q.z);
      a6 += v * bflo(q.w); a7 += v * bfhi(q.w);
    }
  }
  if (active && grp < j1 - j) {     // tail 0..11 edges
    unsigned long long e = __builtin_nontemporal_load(ep + j + grp);
    uint4 q = gb4[(size_t)(unsigned)(e & 0x1FFFFu) * 5 + fi];
    float v = __uint_as_float((unsigned)(e >> 32));
    a0 += v * bflo(q.x); a1 += v * bfhi(q.x);
    a2 += v * bflo(q.y); a3 += v * bfhi(q.y);
    a4 += v * bflo(q.z); a5 += v * bfhi(q.z);
    a6 += v * bflo(q.w); a7 += v * bfhi(q.w);
  }
  // merge 12 groups of 5 lanes: +30, +15, then +5 and +10
  float t0, t1, t2, t3, t4, t5, t6, t7;
  t0 = __shfl(a0, lane + 30, 64); t1 = __shfl(a1, lane + 30, 64);
  t2 = __shfl(a2, lane + 30, 64); t3 = __shfl(a3, lane + 30, 64);
  t4 = __shfl(a4, lane + 30, 64); t5 = __shfl(a5, lane + 30, 64);
  t6 = __shfl(a6, lane + 30, 64); t7 = __shfl(a7, lane + 30, 64);
  if (lane < 30) { a0 += t0; a1 += t1; a2 += t2; a3 += t3;
                   a4 += t4; a5 += t5; a6 += t6; a7 += t7; }
  t0 = __shfl(a0, lane + 15, 64); t1 = __shfl(a1, lane + 15, 64);
  t2 = __shfl(a2, lane + 15, 64); t3 = __shfl(a3, lane + 15, 64);
  t4 = __shfl(a4, lane + 15, 64); t5 = __shfl(a5, lane + 15, 64);
  t6 = __shfl(a6, lane + 15, 64); t7 = __shfl(a7, lane + 15, 64);
  if (lane < 15) { a0 += t0; a1 += t1; a2 += t2; a3 += t3;
                   a4 += t4; a5 += t5; a6 += t6; a7 += t7; }
  float u0, u1, u2, u3, u4, u5, u6, u7;
  t0 = __shfl(a0, lane + 5, 64);  t1 = __shfl(a1, lane + 5, 64);
  t2 = __shfl(a2, lane + 5, 64);  t3 = __shfl(a3, lane + 5, 64);
  t4 = __shfl(a4, lane + 5, 64);  t5 = __shfl(a5, lane + 5, 64);
  t6 = __shfl(a6, lane + 5, 64);  t7 = __shfl(a7, lane + 5, 64);
  u0 = __shfl(a0, lane + 10, 64); u1 = __shfl(a1, lane + 10, 64);
  u2 = __shfl(a2, lane + 10, 64); u3 = __shfl(a3, lane + 10, 64);
  u4 = __shfl(a4, lane + 10, 64); u5 = __shfl(a5, lane + 10, 64);
  u6 = __shfl(a6, lane + 10, 64); u7 = __shfl(a7, lane + 10, 64);
  if (lane < 5) {
    a0 += t0 + u0; a1 += t1 + u1; a2 += t2 + u2; a3 += t3 + u3;
    a4 += t4 + u4; a5 += t5 + u5; a6 += t6 + u6; a7 += t7 + u7;
    f32x4 o0 = {a0, a1, a2, a3};
    f32x4 o1 = {a4, a5, a6, a7};
    __builtin_nontemporal_store(o0, (f32x4*)(out + (size_t)node * F_OUT + fi * 8));
    __builtin_nontemporal_store(o1, (f32x4*)(out + (size_t)node * F_OUT + fi * 8 + 4));
  }
}

extern "C" void kernel_launch(void* const* d_in, const int* in_sizes, int n_in,
                              void* d_out, int out_size, void* d_ws, size_t ws_size,
                              hipStream_t stream) {
  const int* src = (const int*)d_in[0];
  const int* dst = (const int*)d_in[1];
  const float* vals = (const float*)d_in[2];
  const float* x = (const float*)d_in[3];
  const float* W1 = (const float*)d_in[4];
  const float* W2 = (const float*)d_in[5];
  float* out = (float*)d_out;

  // 16B-aligned workspace layout (~37.9 MB)
  int* rs = (int*)d_ws;                            // 80001 used, pad to 80004
  int* counts = rs + 80004;                        // 320*313 = 100160 ints
  int* btot = counts + 100160;                     // 313, pad to 320
  int* bbase = btot + 320;                         // 314, pad to 320
  int2* epack = (int2*)(bbase + 320);              // 16B-aligned
  unsigned short* xb = (unsigned short*)(epack + N_EDGES);   // 5.12M bf16
  unsigned short* gb = xb + (size_t)N_NODES * F_IN;          // 3.2M bf16
  unsigned short* sxgb = gb + (size_t)N_NODES * F_OUT;       // 5.12M bf16 (also estg)
  unsigned short* w1p = sxgb + (size_t)N_NODES * F_IN;       // 8192 bf16
  unsigned short* w2p = w1p + 8192;                          // 6144 bf16
  int2* estg = (int2*)sxgb;   // staging aliases sxgb (dead until gather1)

  prep_kernel<<<5056, 256, 0, stream>>>((const float4*)x, (ushort4*)xb,
                                        W1, W2, w1p, w2p);
  histB_kernel<<<B1, 256, 0, stream>>>(src, counts);
  scan2_kernel<<<NB, 320, 0, stream>>>(counts, btot);
  scanT_kernel<<<1, 320, 0, stream>>>(btot, bbase, rs);
  place_kernel<<<B1, 256, 0, stream>>>(src, dst, vals, counts, bbase, estg);
  permute_kernel<<<NB, 512, 0, stream>>>(bbase, estg, epack, rs);
  gather1_kernel<<<(N_NODES * 64 + 255) / 256, 256, 0, stream>>>(
      rs, epack, (const uint4*)xb, (uint4*)sxgb);
  dense_kernel<<<N_NODES / 32, 256, 0, stream>>>(
      (const uint4*)sxgb, (const uint4*)w1p, (const uint4*)w2p, gb);
  spmm2_kernel<<<(N_NODES * 64 + 255) / 256, 256, 0, stream>>>(
      rs, epack, (const uint4*)gb, out);
}

// Round 18
// 128.597 us; speedup vs baseline: 1.1396x; 1.1396x over previous
//
#include <hip/hip_runtime.h>

#define N_NODES 80000
#define N_EDGES 1280000
#define F_IN 64
#define F_HID 128
#define F_OUT 40
#define NB 313             // src buckets (src>>8), 256 nodes each
#define B1 320             // edge-chunk blocks
#define CHUNK 4000         // edges per chunk block (320*4000 = 1.28M)
#define SAP 72             // sA bf16 stride (row 64 + pad 8)
#define SPP 136            // sP bf16 stride (row 128 + pad 8)

typedef __attribute__((ext_vector_type(8))) short bf16x8;
typedef __attribute__((ext_vector_type(4))) float f32x4;

__device__ __forceinline__ unsigned short bf16rn(float f) {
  unsigned u = __float_as_uint(f);
  u += 0x7fffu + ((u >> 16) & 1u);   // round-to-nearest-even
  return (unsigned short)(u >> 16);
}
__device__ __forceinline__ float bflo(unsigned w) { return __uint_as_float(w << 16); }
__device__ __forceinline__ float bfhi(unsigned w) { return __uint_as_float(w & 0xffff0000u); }

// ---- prep: x -> bf16 (blocks 0..4999) + W1/W2 MFMA-fragment pack (5000..5055) ----
__global__ __launch_bounds__(256) void prep_kernel(const float4* __restrict__ x4,
                                                   ushort4* __restrict__ xb4,
                                                   const float* __restrict__ W1,
                                                   const float* __restrict__ W2,
                                                   unsigned short* __restrict__ w1p,
                                                   unsigned short* __restrict__ w2p) {
  int b = blockIdx.x;
  if (b < 5000) {
    int i = b * 256 + threadIdx.x;     // < 1.28M exactly
    float4 v = x4[i];
    ushort4 o;
    o.x = bf16rn(v.x); o.y = bf16rn(v.y); o.z = bf16rn(v.z); o.w = bf16rn(v.w);
    xb4[i] = o;
  } else {
    int gidx = (b - 5000) * 256 + threadIdx.x;
    if (gidx < 8192) {
      int i = gidx & 7, l = (gidx >> 3) & 63, kf = (gidx >> 9) & 1, nt = gidx >> 10;
      int k = (l >> 4) * 8 + i + kf * 32;
      int c = nt * 16 + (l & 15);
      w1p[gidx] = bf16rn(W1[k * F_HID + c]);
    } else if (gidx < 8192 + 6144) {
      int idx = gidx - 8192;
      int i = idx & 7, l = (idx >> 3) & 63, kf = (idx >> 9) & 3, nt = idx >> 11;
      int k = (l >> 4) * 8 + i + kf * 32;
      int c = nt * 16 + (l & 15);
      w2p[idx] = (c < F_OUT) ? bf16rn(W2[k * F_OUT + c]) : (unsigned short)0;
    }
  }
}

// ---- histB: per-(block,bucket) counts only (LDS histogram, NO global atomics) ----
__global__ __launch_bounds__(256) void histB_kernel(const int* __restrict__ src,
                                                    int* __restrict__ counts) {
  __shared__ int h[NB];
  int tid = threadIdx.x;
  for (int i = tid; i < NB; i += 256) h[i] = 0;
  __syncthreads();
  int base = blockIdx.x * CHUNK;
  for (int i = base + tid; i < base + CHUNK; i += 256)
    atomicAdd(&h[src[i] >> 8], 1);
  __syncthreads();
  for (int i = tid; i < NB; i += 256) counts[blockIdx.x * NB + i] = h[i];
}

// --- scan2: per bucket b, exclusive-scan the 320 block counts; emit bucket total ---
__global__ __launch_bounds__(320) void scan2_kernel(int* __restrict__ counts,
                                                    int* __restrict__ btot) {
  __shared__ int wsum[5];
  __shared__ int woff[5];
  int b = blockIdx.x;
  int t = threadIdx.x, lane = t & 63, w = t >> 6;
  int v = counts[t * NB + b];
  int s = v;
#pragma unroll
  for (int off = 1; off < 64; off <<= 1) {
    int u = __shfl_up(s, off, 64);
    if (lane >= off) s += u;
  }
  if (lane == 63) wsum[w] = s;
  __syncthreads();
  if (t == 0) {
    int acc = 0;
#pragma unroll
    for (int i = 0; i < 5; ++i) { woff[i] = acc; acc += wsum[i]; }
    btot[b] = acc;
  }
  __syncthreads();
  counts[t * NB + b] = (s - v) + woff[w];
}

// --- scanT: one tiny block scans the 313 bucket totals -> bbase ---
__global__ __launch_bounds__(320) void scanT_kernel(const int* __restrict__ btot,
                                                    int* __restrict__ bbase,
                                                    int* __restrict__ rs) {
  __shared__ int wsum[5];
  __shared__ int woff[5];
  int t = threadIdx.x, lane = t & 63, w = t >> 6;
  int v = (t < NB) ? btot[t] : 0;
  int s = v;
#pragma unroll
  for (int off = 1; off < 64; off <<= 1) {
    int u = __shfl_up(s, off, 64);
    if (lane >= off) s += u;
  }
  if (lane == 63) wsum[w] = s;
  __syncthreads();
  if (t == 0) {
    int acc = 0;
#pragma unroll
    for (int i = 0; i < 5; ++i) { woff[i] = acc; acc += wsum[i]; }
  }
  __syncthreads();
  if (t < NB) bbase[t] = (s - v) + woff[w];
  if (t == 0) { bbase[NB] = N_EDGES; rs[N_NODES] = N_EDGES; }
}

// --- place: stream edges into bucket-grouped staging. Local node in dst bits 17..24.
__global__ __launch_bounds__(256) void place_kernel(
    const int* __restrict__ src, const int* __restrict__ dst,
    const float* __restrict__ vals, const int* __restrict__ off,
    const int* __restrict__ bbase, int2* __restrict__ estg) {
  __shared__ int cur[NB];
  int tid = threadIdx.x;
  for (int i = tid; i < NB; i += 256)
    cur[i] = off[blockIdx.x * NB + i] + bbase[i];
  __syncthreads();
  int base = blockIdx.x * CHUNK;
  for (int i = base + tid; i < base + CHUNK; i += 256) {
    int s = src[i];
    int p = atomicAdd(&cur[s >> 8], 1);
    estg[p] = make_int2(dst[i] | ((s & 255) << 17), __float_as_int(vals[i]));
  }
}

// --- permute: one block per bucket. Pass 1: per-node degree + block scan -> rs.
// Pass 2: scatter staged edges to final slots (one XCD per 32KB window).
__global__ __launch_bounds__(512) void permute_kernel(const int* __restrict__ bbase,
                                                      const int2* __restrict__ estg,
                                                      int2* __restrict__ epack,
                                                      int* __restrict__ rs) {
  __shared__ int cnt[256];
  __shared__ int cur[256];
  __shared__ int wsum[4];
  __shared__ int woff[4];
  int b = blockIdx.x, tid = threadIdx.x;
  int nb0 = b << 8;
  int ebase = bbase[b], eend = bbase[b + 1];
  if (tid < 256) cnt[tid] = 0;
  __syncthreads();
  for (int e = ebase + tid; e < eend; e += 512) {
    int2 v = estg[e];
    atomicAdd(&cnt[(v.x >> 17) & 255], 1);
  }
  __syncthreads();
  int lane = tid & 63, w = tid >> 6;
  int v = (tid < 256) ? cnt[tid] : 0;
  int s = v;
#pragma unroll
  for (int off = 1; off < 64; off <<= 1) {
    int u = __shfl_up(s, off, 64);
    if (lane >= off) s += u;
  }
  if (tid < 256 && lane == 63) wsum[w] = s;
  __syncthreads();
  if (tid == 0) {
    int acc = 0;
#pragma unroll
    for (int i = 0; i < 4; ++i) { woff[i] = acc; acc += wsum[i]; }
  }
  __syncthreads();
  if (tid < 256) {
    int g = ebase + woff[w] + (s - v);
    if (nb0 + tid < N_NODES) rs[nb0 + tid] = g;
    cur[tid] = g;
  }
  __syncthreads();
  for (int e = ebase + tid; e < eend; e += 512) {
    int2 v2 = estg[e];
    int p = atomicAdd(&cur[(v2.x >> 17) & 255], 1);
    epack[p] = make_int2(v2.x & 0x1FFFF, v2.y);
  }
}

// ------ gather1: one wave per row, barrier-free: sxgb[node] = bf16(A@xb row) ------
__global__ __launch_bounds__(256) void gather1_kernel(
    const int* __restrict__ rs, const int2* __restrict__ epack,
    const uint4* __restrict__ xb, uint4* __restrict__ sxgb) {
  int node = (blockIdx.x * 256 + threadIdx.x) >> 6;
  int lane = threadIdx.x & 63;
  if (node >= N_NODES) return;
  int h = lane >> 3;     // 0..7: which of 8 parallel edges
  int fi = lane & 7;     // feature-oct index (feats 8fi..8fi+7)
  int j0 = rs[node], j1 = rs[node + 1];
  float a0 = 0.f, a1 = 0.f, a2 = 0.f, a3 = 0.f;
  float a4 = 0.f, a5 = 0.f, a6 = 0.f, a7 = 0.f;
  int j = j0;
  for (; j + 16 <= j1; j += 16) {   // 16 edges in flight
    int2 e0 = epack[j + h];
    int2 e1 = epack[j + 8 + h];
    uint4 q0 = xb[(size_t)e0.x * 8 + fi];
    uint4 q1 = xb[(size_t)e1.x * 8 + fi];
    float v0 = __int_as_float(e0.y), v1 = __int_as_float(e1.y);
    a0 += v0 * bflo(q0.x); a1 += v0 * bfhi(q0.x);
    a2 += v0 * bflo(q0.y); a3 += v0 * bfhi(q0.y);
    a4 += v0 * bflo(q0.z); a5 += v0 * bfhi(q0.z);
    a6 += v0 * bflo(q0.w); a7 += v0 * bfhi(q0.w);
    a0 += v1 * bflo(q1.x); a1 += v1 * bfhi(q1.x);
    a2 += v1 * bflo(q1.y); a3 += v1 * bfhi(q1.y);
    a4 += v1 * bflo(q1.z); a5 += v1 * bfhi(q1.z);
    a6 += v1 * bflo(q1.w); a7 += v1 * bfhi(q1.w);
  }
  for (; j + 8 <= j1; j += 8) {
    int2 e = epack[j + h];
    uint4 q = xb[(size_t)e.x * 8 + fi];
    float v = __int_as_float(e.y);
    a0 += v * bflo(q.x); a1 += v * bfhi(q.x);
    a2 += v * bflo(q.y); a3 += v * bfhi(q.y);
    a4 += v * bflo(q.z); a5 += v * bfhi(q.z);
    a6 += v * bflo(q.w); a7 += v * bfhi(q.w);
  }
  if (h < j1 - j) {                 // tail 0..7 edges
    int2 e = epack[j + h];
    uint4 q = xb[(size_t)e.x * 8 + fi];
    float v = __int_as_float(e.y);
    a0 += v * bflo(q.x); a1 += v * bfhi(q.x);
    a2 += v * bflo(q.y); a3 += v * bfhi(q.y);
    a4 += v * bflo(q.z); a5 += v * bfhi(q.z);
    a6 += v * bflo(q.w); a7 += v * bfhi(q.w);
  }
#pragma unroll
  for (int m = 8; m <= 32; m <<= 1) {
    a0 += __shfl_xor(a0, m, 64); a1 += __shfl_xor(a1, m, 64);
    a2 += __shfl_xor(a2, m, 64); a3 += __shfl_xor(a3, m, 64);
    a4 += __shfl_xor(a4, m, 64); a5 += __shfl_xor(a5, m, 64);
    a6 += __shfl_xor(a6, m, 64); a7 += __shfl_xor(a7, m, 64);
  }
  if (lane < 8) {
    uint4 o;
    o.x = (unsigned)bf16rn(a0) | ((unsigned)bf16rn(a1) << 16);
    o.y = (unsigned)bf16rn(a2) | ((unsigned)bf16rn(a3) << 16);
    o.z = (unsigned)bf16rn(a4) | ((unsigned)bf16rn(a5) << 16);
    o.w = (unsigned)bf16rn(a6) | ((unsigned)bf16rn(a7) << 16);
    sxgb[(size_t)node * 8 + fi] = o;
  }
}

// ---- dense (MFMA): gb = bf16(relu(sX@W1)@W2), sX = 32 bf16 rows in LDS ----
__global__ __launch_bounds__(256) void dense_kernel(
    const uint4* __restrict__ sxgb, const uint4* __restrict__ w1p4,
    const uint4* __restrict__ w2p4, unsigned short* __restrict__ gb) {
  __shared__ __align__(16) unsigned short sA[32 * SAP];   // 4.6 KB
  __shared__ __align__(16) unsigned short sP[32 * SPP];   // 8.7 KB
  int tid = threadIdx.x, lane = tid & 63, w = tid >> 6;
  int rbase = blockIdx.x * 32;

  {                                   // stage 32 rows x 8 uint4, bf16 direct
    int row = tid >> 3, qi = tid & 7;
    uint4 q = sxgb[blockIdx.x * 256 + tid];
    *(uint4*)&sA[row * SAP + qi * 8] = q;
  }
  __syncthreads();

  int kg = lane >> 4;                 // k-group 0..3 (8 k each)
  int cl = lane & 15;                 // col-in-tile / row-in-tile

  // ---- phase 1: P = relu(A @ W1) ----
  {
    int mt = w & 1;                   // row tile
    int ntb = (w >> 1) * 4;           // col tiles ntb..ntb+3
    int arow = mt * 16 + cl;
    bf16x8 a0 = *(const bf16x8*)&sA[arow * SAP + kg * 8];
    bf16x8 a1 = *(const bf16x8*)&sA[arow * SAP + 32 + kg * 8];
    int prow = mt * 16 + kg * 4;
#pragma unroll
    for (int t = 0; t < 4; ++t) {
      int nt = ntb + t;
      f32x4 acc = {0.f, 0.f, 0.f, 0.f};
      bf16x8 b0 = *(const bf16x8*)&w1p4[(nt * 2 + 0) * 64 + lane];
      bf16x8 b1 = *(const bf16x8*)&w1p4[(nt * 2 + 1) * 64 + lane];
      acc = __builtin_amdgcn_mfma_f32_16x16x32_bf16(a0, b0, acc, 0, 0, 0);
      acc = __builtin_amdgcn_mfma_f32_16x16x32_bf16(a1, b1, acc, 0, 0, 0);
      int pcol = nt * 16 + cl;
#pragma unroll
      for (int r = 0; r < 4; ++r)
        sP[(prow + r) * SPP + pcol] = bf16rn(fmaxf(acc[r], 0.f));
    }
  }
  __syncthreads();

  // ---- phase 2: out = P @ W2 (N padded to 48, write cols < 40) ----
  {
    int nT = (w < 2) ? 2 : 1;         // waves 0,1: 2 tiles; waves 2,3: 1 tile
    for (int s = 0; s < nT; ++s) {
      int T = w + s * 4;              // 0..5
      int mt = T & 1, nt = T >> 1;
      int arow = mt * 16 + cl;
      f32x4 acc = {0.f, 0.f, 0.f, 0.f};
#pragma unroll
      for (int kf = 0; kf < 4; ++kf) {
        bf16x8 a = *(const bf16x8*)&sP[arow * SPP + kf * 32 + kg * 8];
        bf16x8 b = *(const bf16x8*)&w2p4[(nt * 4 + kf) * 64 + lane];
        acc = __builtin_amdgcn_mfma_f32_16x16x32_bf16(a, b, acc, 0, 0, 0);
      }
      int ocol = nt * 16 + cl;
      if (ocol < F_OUT) {
        int orow = rbase + mt * 16 + kg * 4;
#pragma unroll
        for (int r = 0; r < 4; ++r)
          gb[(size_t)(orow + r) * F_OUT + ocol] = bf16rn(acc[r]);
      }
    }
  }
}

// ------- SPMM2 gather: out = A @ gb (40 bf16 feats = 5 lanes x uint4) -------
__global__ __launch_bounds__(256) void spmm2_kernel(
    const int* __restrict__ rs, const int2* __restrict__ epack,
    const uint4* __restrict__ gb4, float* __restrict__ out) {
  int node = (blockIdx.x * 256 + threadIdx.x) >> 6;
  int lane = threadIdx.x & 63;
  if (node >= N_NODES) return;
  int grp = lane / 5;         // 0..11 live, 12 = idle (lanes 60-63)
  int fi = lane % 5;          // feature oct (feats 8fi..8fi+7)
  bool active = grp < 12;
  int j0 = rs[node], j1 = rs[node + 1];
  float a0 = 0.f, a1 = 0.f, a2 = 0.f, a3 = 0.f;
  float a4 = 0.f, a5 = 0.f, a6 = 0.f, a7 = 0.f;
  int j = j0;
  for (; j + 24 <= j1; j += 24) {   // 24 edges in flight
    if (active) {
      int2 e0 = epack[j + grp];
      int2 e1 = epack[j + 12 + grp];
      uint4 q0 = gb4[(size_t)e0.x * 5 + fi];
      uint4 q1 = gb4[(size_t)e1.x * 5 + fi];
      float v0 = __int_as_float(e0.y), v1 = __int_as_float(e1.y);
      a0 += v0 * bflo(q0.x); a1 += v0 * bfhi(q0.x);
      a2 += v0 * bflo(q0.y); a3 += v0 * bfhi(q0.y);
      a4 += v0 * bflo(q0.z); a5 += v0 * bfhi(q0.z);
      a6 += v0 * bflo(q0.w); a7 += v0 * bfhi(q0.w);
      a0 += v1 * bflo(q1.x); a1 += v1 * bfhi(q1.x);
      a2 += v1 * bflo(q1.y); a3 += v1 * bfhi(q1.y);
      a4 += v1 * bflo(q1.z); a5 += v1 * bfhi(q1.z);
      a6 += v1 * bflo(q1.w); a7 += v1 * bfhi(q1.w);
    }
  }
  for (; j + 12 <= j1; j += 12) {
    if (active) {
      int2 e = epack[j + grp];
      uint4 q = gb4[(size_t)e.x * 5 + fi];
      float v = __int_as_float(e.y);
      a0 += v * bflo(q.x); a1 += v * bfhi(q.x);
      a2 += v * bflo(q.y); a3 += v * bfhi(q.y);
      a4 += v * bflo(q.z); a5 += v * bfhi(q.z);
      a6 += v * bflo(q.w); a7 += v * bfhi(q.w);
    }
  }
  if (active && grp < j1 - j) {     // tail 0..11 edges
    int2 e = epack[j + grp];
    uint4 q = gb4[(size_t)e.x * 5 + fi];
    float v = __int_as_float(e.y);
    a0 += v * bflo(q.x); a1 += v * bfhi(q.x);
    a2 += v * bflo(q.y); a3 += v * bfhi(q.y);
    a4 += v * bflo(q.z); a5 += v * bfhi(q.z);
    a6 += v * bflo(q.w); a7 += v * bfhi(q.w);
  }
  // merge 12 groups of 5 lanes: +30, +15, then +5 and +10
  float t0, t1, t2, t3, t4, t5, t6, t7;
  t0 = __shfl(a0, lane + 30, 64); t1 = __shfl(a1, lane + 30, 64);
  t2 = __shfl(a2, lane + 30, 64); t3 = __shfl(a3, lane + 30, 64);
  t4 = __shfl(a4, lane + 30, 64); t5 = __shfl(a5, lane + 30, 64);
  t6 = __shfl(a6, lane + 30, 64); t7 = __shfl(a7, lane + 30, 64);
  if (lane < 30) { a0 += t0; a1 += t1; a2 += t2; a3 += t3;
                   a4 += t4; a5 += t5; a6 += t6; a7 += t7; }
  t0 = __shfl(a0, lane + 15, 64); t1 = __shfl(a1, lane + 15, 64);
  t2 = __shfl(a2, lane + 15, 64); t3 = __shfl(a3, lane + 15, 64);
  t4 = __shfl(a4, lane + 15, 64); t5 = __shfl(a5, lane + 15, 64);
  t6 = __shfl(a6, lane + 15, 64); t7 = __shfl(a7, lane + 15, 64);
  if (lane < 15) { a0 += t0; a1 += t1; a2 += t2; a3 += t3;
                   a4 += t4; a5 += t5; a6 += t6; a7 += t7; }
  float u0, u1, u2, u3, u4, u5, u6, u7;
  t0 = __shfl(a0, lane + 5, 64);  t1 = __shfl(a1, lane + 5, 64);
  t2 = __shfl(a2, lane + 5, 64);  t3 = __shfl(a3, lane + 5, 64);
  t4 = __shfl(a4, lane + 5, 64);  t5 = __shfl(a5, lane + 5, 64);
  t6 = __shfl(a6, lane + 5, 64);  t7 = __shfl(a7, lane + 5, 64);
  u0 = __shfl(a0, lane + 10, 64); u1 = __shfl(a1, lane + 10, 64);
  u2 = __shfl(a2, lane + 10, 64); u3 = __shfl(a3, lane + 10, 64);
  u4 = __shfl(a4, lane + 10, 64); u5 = __shfl(a5, lane + 10, 64);
  u6 = __shfl(a6, lane + 10, 64); u7 = __shfl(a7, lane + 10, 64);
  if (lane < 5) {
    a0 += t0 + u0; a1 += t1 + u1; a2 += t2 + u2; a3 += t3 + u3;
    a4 += t4 + u4; a5 += t5 + u5; a6 += t6 + u6; a7 += t7 + u7;
    float4 o0; o0.x = a0; o0.y = a1; o0.z = a2; o0.w = a3;
    float4 o1; o1.x = a4; o1.y = a5; o1.z = a6; o1.w = a7;
    *(float4*)&out[(size_t)node * F_OUT + fi * 8] = o0;
    *(float4*)&out[(size_t)node * F_OUT + fi * 8 + 4] = o1;
  }
}

extern "C" void kernel_launch(void* const* d_in, const int* in_sizes, int n_in,
                              void* d_out, int out_size, void* d_ws, size_t ws_size,
                              hipStream_t stream) {
  const int* src = (const int*)d_in[0];
  const int* dst = (const int*)d_in[1];
  const float* vals = (const float*)d_in[2];
  const float* x = (const float*)d_in[3];
  const float* W1 = (const float*)d_in[4];
  const float* W2 = (const float*)d_in[5];
  float* out = (float*)d_out;

  // 16B-aligned workspace layout (~37.9 MB)
  int* rs = (int*)d_ws;                            // 80001 used, pad to 80004
  int* counts = rs + 80004;                        // 320*313 = 100160 ints
  int* btot = counts + 100160;                     // 313, pad to 320
  int* bbase = btot + 320;                         // 314, pad to 320
  int2* epack = (int2*)(bbase + 320);              // 16B-aligned
  unsigned short* xb = (unsigned short*)(epack + N_EDGES);   // 5.12M bf16
  unsigned short* gb = xb + (size_t)N_NODES * F_IN;          // 3.2M bf16
  unsigned short* sxgb = gb + (size_t)N_NODES * F_OUT;       // 5.12M bf16 (also estg)
  unsigned short* w1p = sxgb + (size_t)N_NODES * F_IN;       // 8192 bf16
  unsigned short* w2p = w1p + 8192;                          // 6144 bf16
  int2* estg = (int2*)sxgb;   // staging aliases sxgb (dead until gather1)

  prep_kernel<<<5056, 256, 0, stream>>>((const float4*)x, (ushort4*)xb,
                                        W1, W2, w1p, w2p);
  histB_kernel<<<B1, 256, 0, stream>>>(src, counts);
  scan2_kernel<<<NB, 320, 0, stream>>>(counts, btot);
  scanT_kernel<<<1, 320, 0, stream>>>(btot, bbase, rs);
  place_kernel<<<B1, 256, 0, stream>>>(src, dst, vals, counts, bbase, estg);
  permute_kernel<<<NB, 512, 0, stream>>>(bbase, estg, epack, rs);
  gather1_kernel<<<(N_NODES * 64 + 255) / 256, 256, 0, stream>>>(
      rs, epack, (const uint4*)xb, (uint4*)sxgb);
  dense_kernel<<<N_NODES / 32, 256, 0, stream>>>(
      (const uint4*)sxgb, (const uint4*)w1p, (const uint4*)w2p, gb);
  spmm2_kernel<<<(N_NODES * 64 + 255) / 256, 256, 0, stream>>>(
      rs, epack, (const uint4*)gb, out);
}